// Round 5
// baseline (497.930 us; speedup 1.0000x reference)
//
#include <hip/hip_runtime.h>
#include <hip/hip_fp16.h>

// GCN encoder: out = A' relu(A' (x W1) + b1) W2 + b2, A' = D^-1/2 (A+I) D^-1/2
// Round 5: R4's k_agg was L2-CAPACITY bound: f32 gin = 6.4 MB > 4 MiB per-XCD L2,
// FETCH_SIZE 68.9 MB = random-gather L2 misses. Store g in f16 (3.2 MB -> L2-resident).
// Gather 2 lanes/edge (float4 = 8 halves), f32 LDS accumulate with XOR-swizzled
// feature slots to spread ds_add_f32 banks. Build pipeline unchanged from R4.
// Algebra: g = h*dinv  =>  p[d] = dinv[d] * (g[d] + sum_{s->d} g[s]).

#define NN 100000
#define NE 1600000
#define FI 128
#define FH 16
#define CB 64                  // dst-nodes per bucket
#define NB 1563                // ceil(NN/CB)
#define GC 128                 // edge chunks
#define CHUNK 12500            // NE/GC exactly

// ---------- CSR-bucket build ----------
__global__ __launch_bounds__(256) void k_count(const int* __restrict__ dst,
                                               int* __restrict__ hist) {
    __shared__ int h[NB];
    for (int i = threadIdx.x; i < NB; i += 256) h[i] = 0;
    __syncthreads();
    int base = blockIdx.x * CHUNK;
    int end = base + CHUNK; if (end > NE) end = NE;
    for (int i = base + threadIdx.x; i < end; i += 256)
        atomicAdd(&h[dst[i] >> 6], 1);
    __syncthreads();
    for (int b = threadIdx.x; b < NB; b += 256)
        hist[b * GC + blockIdx.x] = h[b];
}

// exclusive scan over GC chunks within each bucket (one block per bucket)
__global__ __launch_bounds__(GC) void k_scan_blocks(int* __restrict__ hist,
                                                    int* __restrict__ totals) {
    __shared__ int s[GC];
    int tid = threadIdx.x;
    int v = hist[blockIdx.x * GC + tid];
    s[tid] = v;
    __syncthreads();
    #pragma unroll
    for (int off = 1; off < GC; off <<= 1) {
        int t = (tid >= off) ? s[tid - off] : 0;
        __syncthreads();
        s[tid] += t;
        __syncthreads();
    }
    hist[blockIdx.x * GC + tid] = s[tid] - v;   // exclusive within bucket
    if (tid == GC - 1) totals[blockIdx.x] = s[GC - 1];
}

// exclusive scan of NB bucket totals (single block, 2 elems/thread)
__global__ __launch_bounds__(1024) void k_scan_buckets(const int* __restrict__ totals,
                                                       int* __restrict__ bucketStart) {
    __shared__ int s[1024];
    int tid = threadIdx.x;
    int i0 = 2 * tid, i1 = 2 * tid + 1;
    int a = (i0 < NB) ? totals[i0] : 0;
    int b = (i1 < NB) ? totals[i1] : 0;
    s[tid] = a + b;
    __syncthreads();
    #pragma unroll
    for (int off = 1; off < 1024; off <<= 1) {
        int t = (tid >= off) ? s[tid - off] : 0;
        __syncthreads();
        s[tid] += t;
        __syncthreads();
    }
    int excl = s[tid] - (a + b);
    if (i0 < NB) bucketStart[i0] = excl;
    if (i1 < NB) bucketStart[i1] = excl + a;
    if (tid == 0) bucketStart[NB] = NE;
}

__global__ __launch_bounds__(GC) void k_addback(int* __restrict__ hist,
                                                const int* __restrict__ bucketStart) {
    hist[blockIdx.x * GC + threadIdx.x] += bucketStart[blockIdx.x];
}

// scatter: each block's writes to bucket b fill a private contiguous range
__global__ __launch_bounds__(256) void k_scatter(const int* __restrict__ src,
                                                 const int* __restrict__ dst,
                                                 const int* __restrict__ hist,
                                                 int* __restrict__ packed) {
    __shared__ int cur[NB];
    for (int b = threadIdx.x; b < NB; b += 256)
        cur[b] = hist[b * GC + blockIdx.x];
    __syncthreads();
    int base = blockIdx.x * CHUNK;
    int end = base + CHUNK; if (end > NE) end = NE;
    for (int i = base + threadIdx.x; i < end; i += 256) {
        int d = dst[i];
        int b = d >> 6;
        int pos = atomicAdd(&cur[b], 1);
        packed[pos] = src[i] | ((d & 63) << 17);   // src < 2^17, dl in [0,64)
    }
}

// per-node degree via bucket-local LDS counts -> dinv = rsqrt(deg+1)
__global__ __launch_bounds__(256) void k_deg(const int* __restrict__ packed,
                                             const int* __restrict__ bucketStart,
                                             float* __restrict__ dinv) {
    __shared__ int cnt[CB];
    if (threadIdx.x < CB) cnt[threadIdx.x] = 0;
    __syncthreads();
    int s0 = bucketStart[blockIdx.x], s1 = bucketStart[blockIdx.x + 1];
    for (int i = s0 + threadIdx.x; i < s1; i += 256)
        atomicAdd(&cnt[packed[i] >> 17], 1);
    __syncthreads();
    int node = blockIdx.x * CB + threadIdx.x;
    if (threadIdx.x < CB && node < NN)
        dinv[node] = rsqrtf((float)(cnt[threadIdx.x] + 1));
}

// ---------- dense ops ----------
// g1[n,16] = f16( (x[n,128] @ W1[128,16]) * dinv[n] )
__global__ __launch_bounds__(256) void k_gemm1(const float* __restrict__ x,
                                               const float* __restrict__ W1,
                                               const float* __restrict__ dinv,
                                               __half* __restrict__ g1) {
    __shared__ __align__(16) float w[FI * FH];
    __shared__ __align__(16) float xs[16 * 132];   // stride 132: no bank alias
    const float4* x4 = (const float4*)x;
    for (int i = threadIdx.x; i < FI * FH / 4; i += 256)
        ((float4*)w)[i] = ((const float4*)W1)[i];
    int nodeBase = blockIdx.x * 16;
    for (int i = threadIdx.x; i < 16 * 32; i += 256) {
        int node = i >> 5, k4 = i & 31;
        int gn = nodeBase + node;
        float4 v = (gn < NN) ? x4[gn * 32 + k4] : float4{0.f, 0.f, 0.f, 0.f};
        *(float4*)&xs[node * 132 + k4 * 4] = v;
    }
    __syncthreads();
    int ln = threadIdx.x >> 4, j = threadIdx.x & 15;
    float acc = 0.f;
    #pragma unroll
    for (int k = 0; k < FI; ++k) acc += xs[ln * 132 + k] * w[k * FH + j];
    int gn = nodeBase + ln;
    if (gn < NN) g1[gn * FH + j] = __float2half(acc * dinv[gn]);
}

// accumulate 8 halves of edge (d, half-row c) into swizzled LDS acc
__device__ __forceinline__ void acc8(float* acc, int pk, int c, float4 q) {
    int d = pk >> 17;
    const __half2* h2 = (const __half2*)&q;
    float v[8];
    v[0] = __low2float(h2[0]); v[1] = __high2float(h2[0]);
    v[2] = __low2float(h2[1]); v[3] = __high2float(h2[1]);
    v[4] = __low2float(h2[2]); v[5] = __high2float(h2[2]);
    v[6] = __low2float(h2[3]); v[7] = __high2float(h2[3]);
    int r = d & 7;
    int base = d * FH + c * 8;
    #pragma unroll
    for (int jl = 0; jl < 8; ++jl)             // feature c*8+jl stored at slot jl^r
        unsafeAtomicAdd(&acc[base + (jl ^ r)], v[jl]);
}

// block-per-bucket aggregation; 2 lanes/edge each gathering 8 halves (16 B).
// RELU=true:  gh_out = f16(relu(dinv*(g[d]+acc) + b1) * dinv)   (layer-1 -> g2)
// RELU=false: gf_out = dinv*(g[d]+acc)                          (layer-2 -> p2)
template<bool RELU>
__global__ __launch_bounds__(256) void k_agg(const int* __restrict__ packed,
                                             const int* __restrict__ bucketStart,
                                             const __half* __restrict__ gin,
                                             const float* __restrict__ dinv,
                                             const float* __restrict__ b1,
                                             __half* __restrict__ gh_out,
                                             float* __restrict__ gf_out) {
    __shared__ __align__(16) float acc[CB * FH];   // 4 KB
    ((float4*)acc)[threadIdx.x] = float4{0.f, 0.f, 0.f, 0.f};
    __syncthreads();
    int s0 = bucketStart[blockIdx.x], s1 = bucketStart[blockIdx.x + 1];
    int c = threadIdx.x & 1;            // half-row 0/1 (8 features, 16 B)
    int slot = threadIdx.x >> 1;        // 128 edge slots per block
    int e = s0 + slot;
    for (; e + 384 < s1; e += 512) {    // 512 edges in flight per block
        int p0 = packed[e], p1 = packed[e + 128], p2 = packed[e + 256], p3 = packed[e + 384];
        float4 q0 = *(const float4*)(gin + (p0 & 131071) * FH + c * 8);
        float4 q1 = *(const float4*)(gin + (p1 & 131071) * FH + c * 8);
        float4 q2 = *(const float4*)(gin + (p2 & 131071) * FH + c * 8);
        float4 q3 = *(const float4*)(gin + (p3 & 131071) * FH + c * 8);
        acc8(acc, p0, c, q0);
        acc8(acc, p1, c, q1);
        acc8(acc, p2, c, q2);
        acc8(acc, p3, c, q3);
    }
    for (; e < s1; e += 128) {
        int pk = packed[e];
        float4 q = *(const float4*)(gin + (pk & 131071) * FH + c * 8);
        acc8(acc, pk, c, q);
    }
    __syncthreads();
    // epilogue: un-swizzle, add self-loop, scale
    for (int i = threadIdx.x; i < CB * FH; i += 256) {
        int nl = i >> 4, f = i & 15;
        int node = blockIdx.x * CB + nl;
        if (node < NN) {
            float a = acc[nl * FH + (f & 8) + ((f & 7) ^ (nl & 7))];
            float dv = dinv[node];
            float gi = __half2float(gin[node * FH + f]);
            float val = dv * (gi + a);
            if (RELU) {
                val = fmaxf(val + b1[f], 0.f) * dv;
                gh_out[node * FH + f] = __float2half(val);
            } else {
                gf_out[node * FH + f] = val;
            }
        }
    }
}

// out[n,128] = p2[n,16] @ W2[16,128] + b2; 16 nodes/block, float4 stores
__global__ __launch_bounds__(256) void k_gemm2(const float* __restrict__ p2,
                                               const float* __restrict__ W2,
                                               const float* __restrict__ b2,
                                               float* __restrict__ out) {
    __shared__ __align__(16) float w[FH * FI];
    __shared__ float ps[16 * FH];
    __shared__ __align__(16) float bsh[FI];
    for (int i = threadIdx.x; i < FH * FI / 4; i += 256)
        ((float4*)w)[i] = ((const float4*)W2)[i];
    if (threadIdx.x < FI) bsh[threadIdx.x] = b2[threadIdx.x];
    int nodeBase = blockIdx.x * 16;
    {
        int node = threadIdx.x >> 4, k = threadIdx.x & 15;
        int gn = nodeBase + node;
        ps[threadIdx.x] = (gn < NN) ? p2[gn * FH + k] : 0.f;
    }
    __syncthreads();
    int ln = threadIdx.x >> 4;
    float pr[FH];
    #pragma unroll
    for (int k = 0; k < FH; ++k) pr[k] = ps[ln * FH + k];
    int gn = nodeBase + ln;
    if (gn >= NN) return;
    #pragma unroll
    for (int mm = 0; mm < 2; ++mm) {
        int jb = (threadIdx.x & 15) * 4 + 64 * mm;
        float4 a = *(const float4*)&bsh[jb];
        #pragma unroll
        for (int k = 0; k < FH; ++k) {
            float4 wf = *(const float4*)&w[k * FI + jb];
            a.x += pr[k] * wf.x; a.y += pr[k] * wf.y;
            a.z += pr[k] * wf.z; a.w += pr[k] * wf.w;
        }
        *(float4*)&out[gn * FI + jb] = a;
    }
}

extern "C" void kernel_launch(void* const* d_in, const int* in_sizes, int n_in,
                              void* d_out, int out_size, void* d_ws, size_t ws_size,
                              hipStream_t stream) {
    const float* x  = (const float*)d_in[0];
    const int*   ei = (const int*)d_in[1];
    const float* W1 = (const float*)d_in[2];
    const float* b1 = (const float*)d_in[3];
    const float* W2 = (const float*)d_in[4];
    const float* b2 = (const float*)d_in[5];
    float* out = (float*)d_out;

    const int* src = ei;
    const int* dst = ei + NE;

    // workspace (~17.3 MB)
    int*    hist        = (int*)d_ws;             // [NB*GC]
    int*    totals      = hist + NB * GC;         // [NB]
    int*    bucketStart = totals + NB;            // [NB+1]
    int*    packed      = bucketStart + NB + 1;   // [NE]
    float*  dinv        = (float*)(packed + NE);  // [NN]
    __half* gh1         = (__half*)(dinv + NN);   // [NN*FH] f16 g1
    __half* gh2         = gh1 + NN * FH;          // [NN*FH] f16 g2
    float*  p2f         = (float*)(gh2 + NN * FH);// [NN*FH] f32 p2

    k_count       <<<GC, 256, 0, stream>>>(dst, hist);
    k_scan_blocks <<<NB, GC, 0, stream>>>(hist, totals);
    k_scan_buckets<<<1, 1024, 0, stream>>>(totals, bucketStart);
    k_addback     <<<NB, GC, 0, stream>>>(hist, bucketStart);
    k_scatter     <<<GC, 256, 0, stream>>>(src, dst, hist, packed);
    k_deg         <<<NB, 256, 0, stream>>>(packed, bucketStart, dinv);

    k_gemm1       <<<(NN + 15) / 16, 256, 0, stream>>>(x, W1, dinv, gh1);
    k_agg<true>   <<<NB, 256, 0, stream>>>(packed, bucketStart, gh1, dinv, b1, gh2, (float*)nullptr);
    k_agg<false>  <<<NB, 256, 0, stream>>>(packed, bucketStart, gh2, dinv, b1, (__half*)nullptr, p2f);
    k_gemm2       <<<(NN + 15) / 16, 256, 0, stream>>>(p2f, W2, b2, out);
}

// Round 6
// 366.362 us; speedup vs baseline: 1.3591x; 1.3591x over previous
//
#include <hip/hip_runtime.h>
#include <hip/hip_fp16.h>

// GCN encoder: out = A' relu(A' (x W1) + b1) W2 + b2, A' = D^-1/2 (A+I) D^-1/2
// Round 6: block-per-bucket LDS agg was a LATENCY floor (154-177us regardless of
// traffic: 1563 blocks x ~2 iters can't hide scatter latency). R1's edge-parallel
// atomic push (400k one-shot waves) did the same work in 87us. Revive it with:
// f16 features (3.2 MB, L2-class gathers) + packed pk_add_f16 atomics (12.8M, half
// the write bytes), no CSR build at all, self-loop init fused into gemm1/post1,
// final dinv scale folded into gemm2. Algebra: g=h*dinv; p[d]=dinv_d*(g_d+sum g_s).

#define NN 100000
#define NE 1600000
#define FI 128
#define FH 16

__global__ void k_zero(int* __restrict__ cnt, int n) {
    int i = blockIdx.x * blockDim.x + threadIdx.x;
    if (i < n) cnt[i] = 0;
}

__global__ void k_hist(const int* __restrict__ dst, int* __restrict__ cnt, int e) {
    int i = blockIdx.x * blockDim.x + threadIdx.x;
    if (i < e) atomicAdd(&cnt[dst[i]], 1);
}

__global__ void k_dinv(const int* __restrict__ cnt, float* __restrict__ dinv, int n) {
    int i = blockIdx.x * blockDim.x + threadIdx.x;
    if (i < n) dinv[i] = rsqrtf((float)(cnt[i] + 1));   // +1 self-loop
}

// g1 = f16((x @ W1) * dinv); also writes p1 init = g1 (self-loop term)
__global__ __launch_bounds__(256) void k_gemm1(const float* __restrict__ x,
                                               const float* __restrict__ W1,
                                               const float* __restrict__ dinv,
                                               __half* __restrict__ g1,
                                               __half* __restrict__ p1) {
    __shared__ __align__(16) float w[FI * FH];
    __shared__ __align__(16) float xs[16 * 132];   // stride 132: no bank alias
    const float4* x4 = (const float4*)x;
    for (int i = threadIdx.x; i < FI * FH / 4; i += 256)
        ((float4*)w)[i] = ((const float4*)W1)[i];
    int nodeBase = blockIdx.x * 16;
    for (int i = threadIdx.x; i < 16 * 32; i += 256) {
        int node = i >> 5, k4 = i & 31;
        int gn = nodeBase + node;
        float4 v = (gn < NN) ? x4[gn * 32 + k4] : float4{0.f, 0.f, 0.f, 0.f};
        *(float4*)&xs[node * 132 + k4 * 4] = v;
    }
    __syncthreads();
    int ln = threadIdx.x >> 4, j = threadIdx.x & 15;
    float acc = 0.f;
    #pragma unroll
    for (int k = 0; k < FI; ++k) acc += xs[ln * 132 + k] * w[k * FH + j];
    int gn = nodeBase + ln;
    if (gn < NN) {
        __half v = __float2half(acc * dinv[gn]);
        g1[gn * FH + j] = v;
        p1[gn * FH + j] = v;     // self-loop init for the atomic accumulation
    }
}

// edge-parallel push: p[dst] += g[src]; 8 threads/edge, one half2 pk-atomic each.
// Massive TLP (12.8M one-shot threads) hides the random-gather latency.
__global__ __launch_bounds__(256) void k_prop(const int* __restrict__ src,
                                              const int* __restrict__ dst,
                                              const __half2* __restrict__ g,   // [NN*8]
                                              __half2* __restrict__ p) {       // [NN*8]
    int i = blockIdx.x * 256 + threadIdx.x;
    int e = i >> 3, c = i & 7;
    int s = src[e], d = dst[e];
    __half2 v = g[s * 8 + c];
    unsafeAtomicAdd(&p[d * 8 + c], v);
}

// h2 = relu(dinv*S1 + b1); g2 = f16(h2*dinv); p2 init = g2
__global__ void k_post1(const __half* __restrict__ p1, const float* __restrict__ b1,
                        const float* __restrict__ dinv,
                        __half* __restrict__ g2, __half* __restrict__ p2, int n16) {
    int i = blockIdx.x * blockDim.x + threadIdx.x;
    if (i < n16) {
        float dv = dinv[i >> 4];
        float val = fmaxf(dv * __half2float(p1[i]) + b1[i & 15], 0.f) * dv;
        __half h = __float2half(val);
        g2[i] = h;
        p2[i] = h;
    }
}

// out[n,128] = (dinv[n]*S2[n,16]) @ W2[16,128] + b2; 16 nodes/block
__global__ __launch_bounds__(256) void k_gemm2(const __half* __restrict__ p2,
                                               const float* __restrict__ W2,
                                               const float* __restrict__ b2,
                                               const float* __restrict__ dinv,
                                               float* __restrict__ out) {
    __shared__ __align__(16) float w[FH * FI];
    __shared__ float ps[16 * FH];
    __shared__ __align__(16) float bsh[FI];
    for (int i = threadIdx.x; i < FH * FI / 4; i += 256)
        ((float4*)w)[i] = ((const float4*)W2)[i];
    if (threadIdx.x < FI) bsh[threadIdx.x] = b2[threadIdx.x];
    int nodeBase = blockIdx.x * 16;
    {
        int node = threadIdx.x >> 4, k = threadIdx.x & 15;
        int gn = nodeBase + node;
        ps[threadIdx.x] = (gn < NN) ? __half2float(p2[gn * FH + k]) * dinv[gn] : 0.f;
    }
    __syncthreads();
    int ln = threadIdx.x >> 4;
    float pr[FH];
    #pragma unroll
    for (int k = 0; k < FH; ++k) pr[k] = ps[ln * FH + k];
    int gn = nodeBase + ln;
    if (gn >= NN) return;
    #pragma unroll
    for (int mm = 0; mm < 2; ++mm) {
        int jb = (threadIdx.x & 15) * 4 + 64 * mm;
        float4 a = *(const float4*)&bsh[jb];
        #pragma unroll
        for (int k = 0; k < FH; ++k) {
            float4 wf = *(const float4*)&w[k * FI + jb];
            a.x += pr[k] * wf.x; a.y += pr[k] * wf.y;
            a.z += pr[k] * wf.z; a.w += pr[k] * wf.w;
        }
        *(float4*)&out[gn * FI + jb] = a;
    }
}

extern "C" void kernel_launch(void* const* d_in, const int* in_sizes, int n_in,
                              void* d_out, int out_size, void* d_ws, size_t ws_size,
                              hipStream_t stream) {
    const float* x  = (const float*)d_in[0];
    const int*   ei = (const int*)d_in[1];
    const float* W1 = (const float*)d_in[2];
    const float* b1 = (const float*)d_in[3];
    const float* W2 = (const float*)d_in[4];
    const float* b2 = (const float*)d_in[5];
    float* out = (float*)d_out;

    const int* src = ei;
    const int* dst = ei + NE;

    // workspace (~13.7 MB)
    int*    cnt  = (int*)d_ws;                    // [NN]
    float*  dinv = (float*)(cnt + NN);            // [NN]
    __half* g1   = (__half*)(dinv + NN);          // [NN*FH]
    __half* p1   = g1 + NN * FH;                  // [NN*FH]
    __half* g2   = p1 + NN * FH;                  // [NN*FH]
    __half* p2   = g2 + NN * FH;                  // [NN*FH]

    const int n16 = NN * FH;

    k_zero <<<(NN + 255) / 256, 256, 0, stream>>>(cnt, NN);
    k_hist <<<(NE + 255) / 256, 256, 0, stream>>>(dst, cnt, NE);
    k_dinv <<<(NN + 255) / 256, 256, 0, stream>>>(cnt, dinv, NN);

    k_gemm1<<<(NN + 15) / 16, 256, 0, stream>>>(x, W1, dinv, g1, p1);
    k_prop <<<NE * 8 / 256, 256, 0, stream>>>(src, dst, (const __half2*)g1, (__half2*)p1);
    k_post1<<<(n16 + 255) / 256, 256, 0, stream>>>(p1, b1, dinv, g2, p2, n16);
    k_prop <<<NE * 8 / 256, 256, 0, stream>>>(src, dst, (const __half2*)g2, (__half2*)p2);
    k_gemm2<<<(NN + 15) / 16, 256, 0, stream>>>(p2, W2, b2, dinv, out);
}

// Round 7
// 234.174 us; speedup vs baseline: 2.1263x; 1.5645x over previous
//
#include <hip/hip_runtime.h>
#include <hip/hip_fp16.h>

// GCN encoder: out = A' relu(A' (x W1) + b1) W2 + b2, A' = D^-1/2 (A+I) D^-1/2
// Round 7: (a) exact CSR via multisplit (R4-proven contiguous scatter) + per-bucket
// int-LDS sort; (b) atomic-free gather agg: 8 threads/node, f32 register accum,
// NO LDS float atomics (R3-R5's 155us floor was the shared-mem unsafeAtomicAdd
// pathology); (c) register-blocked gemms (4nx4f/thread, ds_read_b128) — old gemm1
// was LDS-pipe bound (~2 ds_read_b32 per FMA ~ 60us).
// Algebra: g = h*dinv  =>  p[d] = dinv[d] * (g[d] + sum_{s->d} g[s]).

#define NN 100000
#define NE 1600000
#define FI 128
#define FH 16
#define CB 64                  // nodes per bucket
#define NB 1563                // ceil(NN/64); NB*64 = 100032
#define GC 128                 // edge chunks
#define CHUNK 12500            // NE/GC exactly

__device__ __forceinline__ float fc(const float4& v, int i) {
    return i == 0 ? v.x : i == 1 ? v.y : i == 2 ? v.z : v.w;
}

// ---------- CSR build ----------
__global__ __launch_bounds__(256) void k_count(const int* __restrict__ dst,
                                               int* __restrict__ hist) {
    __shared__ int h[NB];
    for (int i = threadIdx.x; i < NB; i += 256) h[i] = 0;
    __syncthreads();
    int base = blockIdx.x * CHUNK;
    for (int i = base + threadIdx.x; i < base + CHUNK; i += 256)
        atomicAdd(&h[dst[i] >> 6], 1);
    __syncthreads();
    for (int b = threadIdx.x; b < NB; b += 256)
        hist[b * GC + blockIdx.x] = h[b];
}

__global__ __launch_bounds__(GC) void k_scan_blocks(int* __restrict__ hist,
                                                    int* __restrict__ totals) {
    __shared__ int s[GC];
    int tid = threadIdx.x;
    int v = hist[blockIdx.x * GC + tid];
    s[tid] = v;
    __syncthreads();
    #pragma unroll
    for (int off = 1; off < GC; off <<= 1) {
        int t = (tid >= off) ? s[tid - off] : 0;
        __syncthreads();
        s[tid] += t;
        __syncthreads();
    }
    hist[blockIdx.x * GC + tid] = s[tid] - v;
    if (tid == GC - 1) totals[blockIdx.x] = s[GC - 1];
}

__global__ __launch_bounds__(1024) void k_scan_buckets(const int* __restrict__ totals,
                                                       int* __restrict__ bucketStart,
                                                       int* __restrict__ rowStart) {
    __shared__ int s[1024];
    int tid = threadIdx.x;
    int i0 = 2 * tid, i1 = i0 + 1;
    int a = (i0 < NB) ? totals[i0] : 0;
    int b = (i1 < NB) ? totals[i1] : 0;
    s[tid] = a + b;
    __syncthreads();
    #pragma unroll
    for (int off = 1; off < 1024; off <<= 1) {
        int t = (tid >= off) ? s[tid - off] : 0;
        __syncthreads();
        s[tid] += t;
        __syncthreads();
    }
    int excl = s[tid] - (a + b);
    if (i0 < NB) bucketStart[i0] = excl;
    if (i1 < NB) bucketStart[i1] = excl + a;
    if (tid == 0) { bucketStart[NB] = NE; rowStart[NN] = NE; }
}

__global__ __launch_bounds__(GC) void k_addback(int* __restrict__ hist,
                                                const int* __restrict__ bucketStart) {
    hist[blockIdx.x * GC + threadIdx.x] += bucketStart[blockIdx.x];
}

__global__ __launch_bounds__(256) void k_scatter(const int* __restrict__ src,
                                                 const int* __restrict__ dst,
                                                 const int* __restrict__ hist,
                                                 int* __restrict__ packed) {
    __shared__ int cur[NB];
    for (int b = threadIdx.x; b < NB; b += 256)
        cur[b] = hist[b * GC + blockIdx.x];
    __syncthreads();
    int base = blockIdx.x * CHUNK;
    for (int i = base + threadIdx.x; i < base + CHUNK; i += 256) {
        int d = dst[i];
        int pos = atomicAdd(&cur[d >> 6], 1);
        packed[pos] = src[i] | ((d & 63) << 17);   // src < 2^17, local node in [0,64)
    }
}

// per-bucket sort -> exact CSR + rowStart + dinv (int LDS atomics only)
__global__ __launch_bounds__(256) void k_bsort(const int* __restrict__ packed,
                                               const int* __restrict__ bucketStart,
                                               int* __restrict__ csr,
                                               int* __restrict__ rowStart,
                                               float* __restrict__ dinv) {
    __shared__ int cnt[CB];
    __shared__ int rs[CB];
    __shared__ int cur[CB];
    if (threadIdx.x < CB) cnt[threadIdx.x] = 0;
    __syncthreads();
    int s0 = bucketStart[blockIdx.x], s1 = bucketStart[blockIdx.x + 1];
    for (int i = s0 + threadIdx.x; i < s1; i += 256)
        atomicAdd(&cnt[(packed[i] >> 17) & 63], 1);
    __syncthreads();
    if (threadIdx.x < CB) rs[threadIdx.x] = cnt[threadIdx.x];
    __syncthreads();
    #pragma unroll
    for (int off = 1; off < CB; off <<= 1) {
        int t = 0;
        if (threadIdx.x < CB && threadIdx.x >= off) t = rs[threadIdx.x - off];
        __syncthreads();
        if (threadIdx.x < CB) rs[threadIdx.x] += t;
        __syncthreads();
    }
    if (threadIdx.x < CB) {
        int start = s0 + rs[threadIdx.x] - cnt[threadIdx.x];   // exclusive
        cur[threadIdx.x] = start;
        int node = blockIdx.x * CB + threadIdx.x;
        if (node < NN) {
            rowStart[node] = start;
            dinv[node] = rsqrtf((float)(cnt[threadIdx.x] + 1));
        }
    }
    __syncthreads();
    for (int i = s0 + threadIdx.x; i < s1; i += 256) {
        int pk = packed[i];
        int pos = atomicAdd(&cur[(pk >> 17) & 63], 1);
        csr[pos] = pk & 131071;
    }
}

// ---------- dense ops ----------
// g1 = f16((x @ W1) * dinv); 256 nodes/block, thread = 4 nodes x 4 feats
__global__ __launch_bounds__(256) void k_gemm1(const float* __restrict__ x,
                                               const float* __restrict__ W1,
                                               const float* __restrict__ dinv,
                                               __half2* __restrict__ g1) {
    __shared__ __align__(16) float w[FI * FH];
    float4* w4s = (float4*)w;
    w4s[threadIdx.x] = ((const float4*)W1)[threadIdx.x];
    w4s[threadIdx.x + 256] = ((const float4*)W1)[threadIdx.x + 256];
    __syncthreads();
    int fg = threadIdx.x & 3;          // feature quad: f = fg*4..fg*4+3
    int ng = threadIdx.x >> 2;         // node group
    int r0 = blockIdx.x * 256 + ng * 4;
    const float4* x4 = (const float4*)x;
    int rr[4]; bool val[4];
    #pragma unroll
    for (int i = 0; i < 4; ++i) {
        val[i] = (r0 + i < NN);
        rr[i] = val[i] ? r0 + i : NN - 1;
    }
    float acc[4][4];
    #pragma unroll
    for (int i = 0; i < 4; ++i)
        #pragma unroll
        for (int j = 0; j < 4; ++j) acc[i][j] = 0.f;
    #pragma unroll 2
    for (int k4 = 0; k4 < 32; ++k4) {
        float4 xv[4];
        #pragma unroll
        for (int i = 0; i < 4; ++i) xv[i] = x4[rr[i] * 32 + k4];
        #pragma unroll
        for (int kk = 0; kk < 4; ++kk) {
            float4 wv = w4s[(k4 * 4 + kk) * 4 + fg];
            #pragma unroll
            for (int i = 0; i < 4; ++i) {
                float xk = fc(xv[i], kk);
                acc[i][0] += xk * wv.x; acc[i][1] += xk * wv.y;
                acc[i][2] += xk * wv.z; acc[i][3] += xk * wv.w;
            }
        }
    }
    #pragma unroll
    for (int i = 0; i < 4; ++i) if (val[i]) {
        float dv = dinv[rr[i]];
        g1[rr[i] * 8 + fg * 2]     = __floats2half2_rn(acc[i][0] * dv, acc[i][1] * dv);
        g1[rr[i] * 8 + fg * 2 + 1] = __floats2half2_rn(acc[i][2] * dv, acc[i][3] * dv);
    }
}

// gather agg: 8 threads/node, f32 register accumulation, zero atomics.
// RELU=true:  g2 = f16(relu(dinv*(g_d + sum) + b1) * dinv)
// RELU=false: p2 = dinv*(g_d + sum)   (f32)
template<bool RELU>
__global__ __launch_bounds__(256) void k_agg(const int* __restrict__ csr,
                                             const int* __restrict__ rowStart,
                                             const __half2* __restrict__ gin,
                                             const float* __restrict__ dinv,
                                             const float* __restrict__ b1,
                                             __half2* __restrict__ gh_out,
                                             float2* __restrict__ p2f) {
    int gid = blockIdx.x * 256 + threadIdx.x;
    int node = gid >> 3, c = gid & 7;
    if (node >= NN) return;
    int s0 = rowStart[node], s1 = rowStart[node + 1];
    float2 acc = __half22float2(gin[node * 8 + c]);   // self-loop term
    int e = s0;
    for (; e + 3 < s1; e += 4) {
        int i0 = csr[e], i1 = csr[e + 1], i2 = csr[e + 2], i3 = csr[e + 3];
        float2 f0 = __half22float2(gin[i0 * 8 + c]);
        float2 f1 = __half22float2(gin[i1 * 8 + c]);
        float2 f2 = __half22float2(gin[i2 * 8 + c]);
        float2 f3 = __half22float2(gin[i3 * 8 + c]);
        acc.x += (f0.x + f1.x) + (f2.x + f3.x);
        acc.y += (f0.y + f1.y) + (f2.y + f3.y);
    }
    for (; e < s1; ++e) {
        float2 f = __half22float2(gin[csr[e] * 8 + c]);
        acc.x += f.x; acc.y += f.y;
    }
    float dv = dinv[node];
    if (RELU) {
        float2 bb = *(const float2*)(b1 + 2 * c);
        float vx = fmaxf(dv * acc.x + bb.x, 0.f) * dv;
        float vy = fmaxf(dv * acc.y + bb.y, 0.f) * dv;
        gh_out[node * 8 + c] = __floats2half2_rn(vx, vy);
    } else {
        p2f[node * 8 + c] = make_float2(dv * acc.x, dv * acc.y);
    }
}

// out = p2 @ W2 + b2; 32 nodes/block, thread = 4 nodes x 4 feats
__global__ __launch_bounds__(256) void k_gemm2(const float* __restrict__ p2s,
                                               const float* __restrict__ W2,
                                               const float* __restrict__ b2,
                                               float* __restrict__ out) {
    __shared__ __align__(16) float w[FH * FI];
    __shared__ __align__(16) float pst[FH][32];   // transposed p2 tile
    float4* w4s = (float4*)w;
    w4s[threadIdx.x] = ((const float4*)W2)[threadIdx.x];
    w4s[threadIdx.x + 256] = ((const float4*)W2)[threadIdx.x + 256];
    int base = blockIdx.x * 32;
    {
        int n = threadIdx.x >> 4, k = threadIdx.x & 15;
        int gn = base + n;
        pst[k][n] = (gn < NN) ? p2s[gn * 16 + k] : 0.f;
        n += 16; gn = base + n;
        pst[k][n] = (gn < NN) ? p2s[gn * 16 + k] : 0.f;
    }
    __syncthreads();
    int fg = threadIdx.x & 31;    // feature quad: f = fg*4..fg*4+3
    int ng = threadIdx.x >> 5;    // node group: n = ng*4..ng*4+3
    float4 bb = ((const float4*)b2)[fg];
    float acc[4][4];
    #pragma unroll
    for (int i = 0; i < 4; ++i) {
        acc[i][0] = bb.x; acc[i][1] = bb.y; acc[i][2] = bb.z; acc[i][3] = bb.w;
    }
    #pragma unroll
    for (int k = 0; k < FH; ++k) {
        float4 xk = *(float4*)&pst[k][ng * 4];
        float4 wv = w4s[k * 32 + fg];
        #pragma unroll
        for (int i = 0; i < 4; ++i) {
            float xv = fc(xk, i);
            acc[i][0] += xv * wv.x; acc[i][1] += xv * wv.y;
            acc[i][2] += xv * wv.z; acc[i][3] += xv * wv.w;
        }
    }
    #pragma unroll
    for (int i = 0; i < 4; ++i) {
        int gn = base + ng * 4 + i;
        if (gn < NN)
            ((float4*)out)[gn * 32 + fg] =
                make_float4(acc[i][0], acc[i][1], acc[i][2], acc[i][3]);
    }
}

extern "C" void kernel_launch(void* const* d_in, const int* in_sizes, int n_in,
                              void* d_out, int out_size, void* d_ws, size_t ws_size,
                              hipStream_t stream) {
    const float* x  = (const float*)d_in[0];
    const int*   ei = (const int*)d_in[1];
    const float* W1 = (const float*)d_in[2];
    const float* b1 = (const float*)d_in[3];
    const float* W2 = (const float*)d_in[4];
    const float* b2 = (const float*)d_in[5];
    float* out = (float*)d_out;

    const int* src = ei;
    const int* dst = ei + NE;

    // workspace layout (20.8 MB total, 4-B units)
    int*   hist        = (int*)d_ws;               // [NB*GC] 200064
    int*   totals      = hist + NB * GC;           // [NB]
    int*   bucketStart = totals + NB;              // [NB+1]
    int*   rowStart    = bucketStart + NB + 1;     // [NN+1]
    float* dinv        = (float*)(rowStart + NN + 1); // [NN]
    int*   csr         = (int*)(dinv + NN);        // [NE]
    int*   packed      = csr + NE;                 // [NE] -> reused as g1,g2
    __half2* g1        = (__half2*)packed;         // [NN*8] (800k ints)
    __half2* g2        = g1 + NN * 8;              // [NN*8] (800k ints)
    float2*  p2f       = (float2*)(packed + NE);   // [NN*8] (1.6M ints)

    k_count       <<<GC, 256, 0, stream>>>(dst, hist);
    k_scan_blocks <<<NB, GC, 0, stream>>>(hist, totals);
    k_scan_buckets<<<1, 1024, 0, stream>>>(totals, bucketStart, rowStart);
    k_addback     <<<NB, GC, 0, stream>>>(hist, bucketStart);
    k_scatter     <<<GC, 256, 0, stream>>>(src, dst, hist, packed);
    k_bsort       <<<NB, 256, 0, stream>>>(packed, bucketStart, csr, rowStart, dinv);

    k_gemm1       <<<(NN + 255) / 256, 256, 0, stream>>>(x, W1, dinv, g1);
    k_agg<true>   <<<(NN * 8) / 256, 256, 0, stream>>>(csr, rowStart, g1, dinv, b1, g2, (float2*)nullptr);
    k_agg<false>  <<<(NN * 8) / 256, 256, 0, stream>>>(csr, rowStart, g2, dinv, b1, (__half2*)nullptr, p2f);
    k_gemm2       <<<(NN + 31) / 32, 256, 0, stream>>>((const float*)p2f, W2, b2, out);
}